// Round 13
// baseline (2521.146 us; speedup 1.0000x reference)
//
#include <hip/hip_runtime.h>

// Problem constants: B=8, N=16384, NPOINT=1024, NSAMPLE=32, RADIUS=0.4, C_IN=64
#define R2 0.16f  // f32-nearest of python 0.4*0.4 (== nearest f32 to 0.16)

typedef float f32x2 __attribute__((ext_vector_type(2)));

// Packed IEEE RN add/mul (per-component identical to scalar v_add/v_mul) —
// selection logic stays bit-exact vs the reference while halving VALU instrs.
__device__ __forceinline__ f32x2 pk_add(f32x2 a, f32x2 b) {
  f32x2 d;
  asm("v_pk_add_f32 %0, %1, %2" : "=v"(d) : "v"(a), "v"(b));
  return d;
}
__device__ __forceinline__ f32x2 pk_mul(f32x2 a, f32x2 b) {
  f32x2 d;
  asm("v_pk_mul_f32 %0, %1, %2" : "=v"(d) : "v"(a), "v"(b));
  return d;
}

// Exact (non-contracted) squared distance for ball query.
__device__ __forceinline__ float sqd(float x, float y, float z,
                                     float px, float py, float pz) {
  float dx = __fsub_rn(x, px);
  float dy = __fsub_rn(y, py);
  float dz = __fsub_rn(z, pz);
  return __fadd_rn(__fadd_rn(__fmul_rn(dx, dx), __fmul_rn(dy, dy)),
                   __fmul_rn(dz, dz));
}

// Canonical gfx9 wave64 max-reduce via DPP: row_shr 1/2/4/8 then
// row_bcast:15, row_bcast:31. Full-wave max valid in lane 63.
// (Verified correct in R12: passed with absmax 4.88e-4.)
__device__ __forceinline__ float wave64_max_dpp(float x) {
#define DPP_STEP(CTRL)                                                      \
  {                                                                         \
    int t_ = __builtin_amdgcn_update_dpp(__float_as_int(x),                 \
                                         __float_as_int(x), CTRL, 0xf, 0xf, \
                                         false);                            \
    x = fmaxf(x, __int_as_float(t_));                                       \
  }
  DPP_STEP(0x111)  // row_shr:1
  DPP_STEP(0x112)  // row_shr:2
  DPP_STEP(0x114)  // row_shr:4
  DPP_STEP(0x118)  // row_shr:8
  DPP_STEP(0x142)  // row_bcast:15
  DPP_STEP(0x143)  // row_bcast:31
#undef DPP_STEP
  return x;
}

// ---------------- SoA staging: xyz (B,N,3) -> xs/ys/zs (B,N) ----------------
__global__ __launch_bounds__(256) void soa_kernel(const float* __restrict__ xyz,
                                                  float* __restrict__ xs,
                                                  float* __restrict__ ys,
                                                  float* __restrict__ zs) {
  int t = blockIdx.x * 256 + threadIdx.x;  // 0 .. 131071 = (b,n)
  const float* p = xyz + (size_t)t * 3;
  xs[t] = p[0];
  ys[t] = p[1];
  zs[t] = p[2];
}

// ---------------- FPS: one block (1024 thr) per batch, 16 pts/thread ---------
// x,y live in LDS as a THREAD-PRIVATE store (each thread reads only slots it
// wrote — no barrier needed for this data). Rationale: R5/R8/R10/R12 all show
// the register allocator refuses to keep the 48-reg X/Y/Z set resident
// (VGPR=48-96, per-iteration L2 reloads at ~56 B/cyc/CU). LDS gives
// ~112-128 B/cyc/CU and cannot be "rematerialized away". Layout: xylds[q*1024
// + tid] = {x_2q, x_2q+1, y_2q, y_2q+1} (float4, 128 KB dynamic LDS) ->
// ds_read_b128 hits the 8-cyc BW floor, X/Y extract as consecutive reg pairs
// (no movs). z (16 VGPR) + M (16 VGPR) stay registers (~52 total, no
// pressure). Ownership contiguous [tid*16, tid*16+16): lane order == gid
// order; reduce identical to R12 (DPP wave max -> LDS atomicMax on float bits
// -> ballot+ctz lowest lane -> atomicMin (gid<<4|wid) -> coords from LDS).
__global__ __launch_bounds__(1024) void fps_kernel(
    const float* __restrict__ xyz, const float* __restrict__ xs,
    const float* __restrict__ ys, const float* __restrict__ zs,
    int* __restrict__ idx_out) {
  extern __shared__ float4 xylds[];  // 8192 entries = 128 KB
  int b = blockIdx.x;
  int tid = threadIdx.x;
  int lane = tid & 63, wid = tid >> 6;
  const float* xb = xyz + (size_t)b * 16384 * 3;
  int base = tid << 4;  // 16 consecutive points per thread
  const float4* xv = (const float4*)(xs + (size_t)b * 16384 + base);
  const float4* yv = (const float4*)(ys + (size_t)b * 16384 + base);
  const float4* zv = (const float4*)(zs + (size_t)b * 16384 + base);
  float xr[16], yr[16], zr[16];
#pragma unroll
  for (int q = 0; q < 4; ++q) {
    *(float4*)(xr + 4 * q) = xv[q];
    *(float4*)(yr + 4 * q) = yv[q];
    *(float4*)(zr + 4 * q) = zv[q];
  }
  f32x2 Z[8], M[8];
#pragma unroll
  for (int q = 0; q < 8; ++q) {
    xylds[(q << 10) + tid] =
        make_float4(xr[2 * q], xr[2 * q + 1], yr[2 * q], yr[2 * q + 1]);
    Z[q] = {zr[2 * q], zr[2 * q + 1]};
    M[q] = {__builtin_inff(), __builtin_inff()};
  }
  __shared__ unsigned s_vmax[2];
  __shared__ int s_widx[2];
  __shared__ float s_cd[2][3][16];
  if (tid == 0) {
    idx_out[b * 1024] = 0;
    s_vmax[0] = 0u;
    s_vmax[1] = 0u;
    s_widx[0] = 0x7fffffff;
    s_widx[1] = 0x7fffffff;
  }
  __syncthreads();
  float px = xb[0], py = xb[1], pz = xb[2];
  for (int it = 1; it < 1024; ++it) {
    int sl = it & 1;
    // ---- packed sweep (bit-exact vs reference scalar arithmetic)
    f32x2 npx = {-px, -px}, npy = {-py, -py}, npz = {-pz, -pz};
    float tv = -1.0f;
#pragma unroll
    for (int q = 0; q < 8; ++q) {
      float4 t = xylds[(q << 10) + tid];  // {x0,x1,y0,y1}
      f32x2 X, Y;
      X.x = t.x; X.y = t.y;
      Y.x = t.z; Y.y = t.w;
      f32x2 dx = pk_add(X, npx);
      f32x2 dy = pk_add(Y, npy);
      f32x2 dz = pk_add(Z[q], npz);
      f32x2 d = pk_add(pk_add(pk_mul(dx, dx), pk_mul(dy, dy)), pk_mul(dz, dz));
      M[q].x = fminf(M[q].x, d.x);
      M[q].y = fminf(M[q].y, d.y);
      tv = fmaxf(fmaxf(tv, M[q].x), M[q].y);  // fuses to v_max3
    }
    // ---- wave max via DPP (lane 63), one LDS atomicMax per wave
    float bv = wave64_max_dpp(tv);
    if (lane == 63) atomicMax(&s_vmax[sl], (unsigned)__float_as_int(bv));
    __syncthreads();  // bar1: block max ready
    float v = __int_as_float((int)s_vmax[sl]);
    if (tid == 0) {  // reset other slot (readers passed bar1, writers wait bar2)
      s_vmax[sl ^ 1] = 0u;
      s_widx[sl ^ 1] = 0x7fffffff;
    }
    // ---- winner: lowest matching lane per wave -> atomicMin + coords to LDS
    unsigned long long mk = __ballot(tv == v);
    if (mk != 0ull && lane == (int)__builtin_ctzll(mk)) {
      int k = -1;
      float wx = 0.0f, wy = 0.0f, wz = 0.0f;
#pragma unroll
      for (int q = 0; q < 8; ++q) {  // ascending k, first match = lowest gid
        float4 t = xylds[(q << 10) + tid];
        if (k < 0 && M[q].x == v) { k = 2 * q;     wx = t.x; wy = t.z; wz = Z[q].x; }
        if (k < 0 && M[q].y == v) { k = 2 * q + 1; wx = t.y; wy = t.w; wz = Z[q].y; }
      }
      atomicMin(&s_widx[sl], ((base + k) << 4) | wid);
      s_cd[sl][0][wid] = wx;
      s_cd[sl][1][wid] = wy;
      s_cd[sl][2][wid] = wz;
    }
    __syncthreads();  // bar2: winner key + coords visible
    int kmin = s_widx[sl];
    int w = kmin & 15;
    int j = kmin >> 4;
    px = s_cd[sl][0][w];
    py = s_cd[sl][1][w];
    pz = s_cd[sl][2][w];
    if (tid == 0) idx_out[b * 1024 + it] = j;
  }
}

// ---------------- gather new_xyz into d_out[0 .. 24576) ----------------------
__global__ __launch_bounds__(256) void gather_newxyz(const float* __restrict__ xyz,
                                                     const int* __restrict__ idx,
                                                     float* __restrict__ out) {
  int t = blockIdx.x * 256 + threadIdx.x;  // 0..8191 = (b,p)
  int b = t >> 10;
  int i = idx[t];
  const float* src = xyz + ((size_t)b * 16384 + i) * 3;
  float* dst = out + (size_t)t * 3;
  dst[0] = src[0];
  dst[1] = src[1];
  dst[2] = src[2];
}

// ---------------- transpose features (B,64,N) -> (B,N,64) --------------------
__global__ __launch_bounds__(256) void transpose_feats(const float* __restrict__ f,
                                                       float* __restrict__ fT) {
  __shared__ float tile[64][65];
  int b = blockIdx.x >> 8;
  int n0 = (blockIdx.x & 255) << 6;
  int t = threadIdx.x;
  int nn = t & 63, c0 = t >> 6;
#pragma unroll
  for (int r = 0; r < 64; r += 4) {
    int c = c0 + r;
    tile[c][nn] = f[((size_t)b * 64 + c) * 16384 + n0 + nn];
  }
  __syncthreads();
  int cc = t & 63, n1 = t >> 6;
#pragma unroll
  for (int r = 0; r < 64; r += 4) {
    int n = n1 + r;
    fT[((size_t)b * 16384 + n0 + n) * 64 + cc] = tile[cc][n];
  }
}

// ---------------- ball query: one wave per centroid --------------------------
__global__ __launch_bounds__(256) void ballquery_kernel(const float* __restrict__ xyz,
                                                        const float* __restrict__ newxyz,
                                                        int* __restrict__ gidx) {
  int wid = threadIdx.x >> 6, lane = threadIdx.x & 63;
  int cid = blockIdx.x * 4 + wid;  // 0..8191
  int b = cid >> 10;
  const float* xb = xyz + (size_t)b * 16384 * 3;
  float cx = newxyz[cid * 3 + 0];
  float cy = newxyz[cid * 3 + 1];
  float cz = newxyz[cid * 3 + 2];
  int* out = gidx + (size_t)cid * 32;
  int found = 0;
  int first = -1;
  for (int c0 = 0; c0 < 16384; c0 += 64) {
    int g = c0 + lane;
    float xx = xb[g * 3 + 0], yy = xb[g * 3 + 1], zz = xb[g * 3 + 2];
    float d2 = sqd(xx, yy, zz, cx, cy, cz);
    bool inr = (d2 <= R2);
    unsigned long long mask = __ballot(inr);
    if (first < 0 && mask) first = c0 + (int)__builtin_ctzll(mask);
    int pre = __popcll(mask & ((1ull << lane) - 1ull));
    int slot = found + pre;
    if (inr && slot < 32) out[slot] = g;
    found += __popcll(mask);
    if (found >= 32) break;
  }
  for (int s = found + lane; s < 32; s += 64) out[s] = first;
}

// ---------------- fused group + MLP(67->64->64->128) + maxpool ---------------
#define FMA16(BASEPTR)                                                     \
  do {                                                                     \
    const float4* hp_ = (const float4*)(BASEPTR);                          \
    float4 v0 = hp_[0], v1 = hp_[1], v2 = hp_[2], v3 = hp_[3];             \
    float a = acc[s];                                                      \
    a = fmaf(w[0], v0.x, a);  a = fmaf(w[1], v0.y, a);                     \
    a = fmaf(w[2], v0.z, a);  a = fmaf(w[3], v0.w, a);                     \
    a = fmaf(w[4], v1.x, a);  a = fmaf(w[5], v1.y, a);                     \
    a = fmaf(w[6], v1.z, a);  a = fmaf(w[7], v1.w, a);                     \
    a = fmaf(w[8], v2.x, a);  a = fmaf(w[9], v2.y, a);                     \
    a = fmaf(w[10], v2.z, a); a = fmaf(w[11], v2.w, a);                    \
    a = fmaf(w[12], v3.x, a); a = fmaf(w[13], v3.y, a);                    \
    a = fmaf(w[14], v3.z, a); a = fmaf(w[15], v3.w, a);                    \
    acc[s] = a;                                                            \
  } while (0)

__global__ __launch_bounds__(256) void mlp_kernel(
    const float* __restrict__ xyz, const float* __restrict__ feats,
    const float* __restrict__ featsT, const float* __restrict__ newxyz,
    const int* __restrict__ gidx,
    const float* __restrict__ W1, const float* __restrict__ b1,
    const float* __restrict__ W2, const float* __restrict__ b2,
    const float* __restrict__ W3, const float* __restrict__ b3,
    float* __restrict__ out, int useT) {
  __shared__ float buf[4][32 * 68];
  int wid = threadIdx.x >> 6, lane = threadIdx.x & 63;
  int cid = blockIdx.x * 4 + wid;
  int b = cid >> 10, p = cid & 1023;
  float* A = buf[wid];
  const int* gi = gidx + (size_t)cid * 32;
  float cx = newxyz[cid * 3 + 0];
  float cy = newxyz[cid * 3 + 1];
  float cz = newxyz[cid * 3 + 2];

  // ---- stage h0
  if (useT) {
    const float4* fT4 = (const float4*)(featsT + (size_t)b * 16384 * 64);
    for (int t = lane; t < 512; t += 64) {
      int s = t >> 4, q = t & 15;
      int g = gi[s];
      float4 v = fT4[(size_t)g * 16 + q];
      *(float4*)(A + s * 68 + q * 4) = v;
    }
  } else {
    const float* fb = feats + (size_t)b * 64 * 16384;
    for (int t = lane; t < 2048; t += 64) {
      int c = t >> 5, s = t & 31;
      int g = gi[s];
      A[s * 68 + c] = fb[(size_t)c * 16384 + g];
    }
  }
  for (int t = lane; t < 96; t += 64) {
    int s = t / 3, c = t - s * 3;
    int g = gi[s];
    float pv = xyz[((size_t)b * 16384 + g) * 3 + c];
    float cv = (c == 0) ? cx : ((c == 1) ? cy : cz);
    A[s * 68 + 64 + c] = __fsub_rn(pv, cv);
  }
  if (lane < 32) A[lane * 68 + 67] = 0.0f;
  __syncthreads();

  int o = lane;
  float acc[32];

  // ---- L1: 67 -> 64
#pragma unroll
  for (int s = 0; s < 32; ++s) acc[s] = b1[o];
  {
    const float* wr = W1 + o * 67;
    for (int cb = 0; cb < 4; ++cb) {
      float w[16];
#pragma unroll
      for (int q = 0; q < 16; ++q) w[q] = wr[3 + cb * 16 + q];
#pragma unroll
      for (int s = 0; s < 32; ++s) { FMA16(A + s * 68 + cb * 16); }
    }
    float w0 = wr[0], w1 = wr[1], w2 = wr[2];
#pragma unroll
    for (int s = 0; s < 32; ++s) {
      float a = acc[s];
      a = fmaf(w0, A[s * 68 + 64], a);
      a = fmaf(w1, A[s * 68 + 65], a);
      a = fmaf(w2, A[s * 68 + 66], a);
      acc[s] = a;
    }
  }
  __syncthreads();
#pragma unroll
  for (int s = 0; s < 32; ++s) A[s * 64 + o] = fmaxf(acc[s], 0.0f);
  __syncthreads();

  // ---- L2: 64 -> 64
#pragma unroll
  for (int s = 0; s < 32; ++s) acc[s] = b2[o];
  {
    const float* wr = W2 + o * 64;
    for (int cb = 0; cb < 4; ++cb) {
      float w[16];
#pragma unroll
      for (int q = 0; q < 16; ++q) w[q] = wr[cb * 16 + q];
#pragma unroll
      for (int s = 0; s < 32; ++s) { FMA16(A + s * 64 + cb * 16); }
    }
  }
  __syncthreads();
#pragma unroll
  for (int s = 0; s < 32; ++s) A[s * 64 + o] = fmaxf(acc[s], 0.0f);
  __syncthreads();

  // ---- L3: 64 -> 128, fused relu + maxpool over s
  float* outp = out + 24576;
  for (int po = 0; po < 2; ++po) {
    int o2 = lane + (po << 6);
#pragma unroll
    for (int s = 0; s < 32; ++s) acc[s] = b3[o2];
    const float* wr = W3 + o2 * 64;
    for (int cb = 0; cb < 4; ++cb) {
      float w[16];
#pragma unroll
      for (int q = 0; q < 16; ++q) w[q] = wr[cb * 16 + q];
#pragma unroll
      for (int s = 0; s < 32; ++s) { FMA16(A + s * 64 + cb * 16); }
    }
    float mx = 0.0f;  // relu floor
#pragma unroll
    for (int s = 0; s < 32; ++s) mx = fmaxf(mx, acc[s]);
    outp[((size_t)b * 128 + o2) * 1024 + p] = mx;
  }
}

extern "C" void kernel_launch(void* const* d_in, const int* in_sizes, int n_in,
                              void* d_out, int out_size, void* d_ws, size_t ws_size,
                              hipStream_t stream) {
  const float* xyz = (const float*)d_in[0];
  const float* feats = (const float*)d_in[1];
  const float* W1 = (const float*)d_in[2];
  const float* b1 = (const float*)d_in[3];
  const float* W2 = (const float*)d_in[4];
  const float* b2 = (const float*)d_in[5];
  const float* W3 = (const float*)d_in[6];
  const float* b3 = (const float*)d_in[7];
  float* out = (float*)d_out;

  // ws layout: idx 32K | gidx 1M | xs/ys/zs 1.5M | featsT 32M (optional)
  int* idx = (int*)d_ws;
  int* gidx = (int*)((char*)d_ws + 32768);
  float* xs = (float*)((char*)d_ws + 32768 + 1048576);
  float* ys = xs + 131072;
  float* zs = ys + 131072;
  float* featsT = (float*)((char*)d_ws + 32768 + 1048576 + 1572864);
  size_t needT = 32768 + 1048576 + 1572864 +
                 (size_t)8 * 16384 * 64 * sizeof(float);
  int useT = (ws_size >= needT) ? 1 : 0;

  soa_kernel<<<512, 256, 0, stream>>>(xyz, xs, ys, zs);
  fps_kernel<<<8, 1024, 131072, stream>>>(xyz, xs, ys, zs, idx);
  gather_newxyz<<<32, 256, 0, stream>>>(xyz, idx, out);
  if (useT) transpose_feats<<<2048, 256, 0, stream>>>(feats, featsT);
  ballquery_kernel<<<2048, 256, 0, stream>>>(xyz, out, gidx);
  mlp_kernel<<<2048, 256, 0, stream>>>(xyz, feats, featsT, out, gidx,
                                       W1, b1, W2, b2, W3, b3, out, useT);
}

// Round 14
// 2354.373 us; speedup vs baseline: 1.0708x; 1.0708x over previous
//
#include <hip/hip_runtime.h>

// Problem constants: B=8, N=16384, NPOINT=1024, NSAMPLE=32, RADIUS=0.4, C_IN=64
#define R2 0.16f  // f32-nearest of python 0.4*0.4 (== nearest f32 to 0.16)

typedef float f32x2 __attribute__((ext_vector_type(2)));

// Exact (non-contracted) squared distance for ball query.
__device__ __forceinline__ float sqd(float x, float y, float z,
                                     float px, float py, float pz) {
  float dx = __fsub_rn(x, px);
  float dy = __fsub_rn(y, py);
  float dz = __fsub_rn(z, pz);
  return __fadd_rn(__fadd_rn(__fmul_rn(dx, dx), __fmul_rn(dy, dy)),
                   __fmul_rn(dz, dz));
}

// Canonical gfx9 wave64 max-reduce via DPP: row_shr 1/2/4/8 then
// row_bcast:15, row_bcast:31. Full-wave max valid in lane 63.
// (Verified correct in R12/R13: passed with absmax 4.88e-4.)
__device__ __forceinline__ float wave64_max_dpp(float x) {
#define DPP_STEP(CTRL)                                                      \
  {                                                                         \
    int t_ = __builtin_amdgcn_update_dpp(__float_as_int(x),                 \
                                         __float_as_int(x), CTRL, 0xf, 0xf, \
                                         false);                            \
    x = fmaxf(x, __int_as_float(t_));                                       \
  }
  DPP_STEP(0x111)  // row_shr:1
  DPP_STEP(0x112)  // row_shr:2
  DPP_STEP(0x114)  // row_shr:4
  DPP_STEP(0x118)  // row_shr:8
  DPP_STEP(0x142)  // row_bcast:15
  DPP_STEP(0x143)  // row_bcast:31
#undef DPP_STEP
  return x;
}

// ---------------- SoA staging: xyz (B,N,3) -> xs/ys/zs (B,N) ----------------
__global__ __launch_bounds__(256) void soa_kernel(const float* __restrict__ xyz,
                                                  float* __restrict__ xs,
                                                  float* __restrict__ ys,
                                                  float* __restrict__ zs) {
  int t = blockIdx.x * 256 + threadIdx.x;  // 0 .. 131071 = (b,n)
  const float* p = xyz + (size_t)t * 3;
  xs[t] = p[0];
  ys[t] = p[1];
  zs[t] = p[2];
}

// ---------------- FPS: one block (1024 thr) per batch, 16 pts/thread ---------
// Sweep uses NATIVE f32x2 vector arithmetic under fp contract(off):
// clang emits v_pk_add_f32/v_pk_mul_f32 directly, with no inline-asm
// register-placement movs (R12/R13 post-mortem: the asm pk wrappers cost
// ~330 VALU instr/wave/iter vs ~110 expected — mov bloat around every asm).
// contract(off) forbids FMA fusion -> per-component ops are IEEE RN mul/add,
// bit-identical to the reference's ((dx*dx+dy*dy)+dz*dz).
// x,y in LDS (thread-private slots, no barrier); z + M in regs.
// Reduce (verified R12/R13): DPP wave max -> LDS atomicMax on float bits ->
// ballot+ctz lowest lane -> atomicMin (gid<<4|wid) -> coords from LDS.
__global__ __launch_bounds__(1024) void fps_kernel(
    const float* __restrict__ xyz, const float* __restrict__ xs,
    const float* __restrict__ ys, const float* __restrict__ zs,
    int* __restrict__ idx_out) {
#pragma clang fp contract(off)
  extern __shared__ float4 xylds[];  // 8192 entries = 128 KB
  int b = blockIdx.x;
  int tid = threadIdx.x;
  int lane = tid & 63, wid = tid >> 6;
  const float* xb = xyz + (size_t)b * 16384 * 3;
  int base = tid << 4;  // 16 consecutive points per thread
  const float4* xv = (const float4*)(xs + (size_t)b * 16384 + base);
  const float4* yv = (const float4*)(ys + (size_t)b * 16384 + base);
  const float4* zv = (const float4*)(zs + (size_t)b * 16384 + base);
  float xr[16], yr[16], zr[16];
#pragma unroll
  for (int q = 0; q < 4; ++q) {
    *(float4*)(xr + 4 * q) = xv[q];
    *(float4*)(yr + 4 * q) = yv[q];
    *(float4*)(zr + 4 * q) = zv[q];
  }
  f32x2 Z[8], M[8];
#pragma unroll
  for (int q = 0; q < 8; ++q) {
    xylds[(q << 10) + tid] =
        make_float4(xr[2 * q], xr[2 * q + 1], yr[2 * q], yr[2 * q + 1]);
    Z[q] = {zr[2 * q], zr[2 * q + 1]};
    M[q] = {__builtin_inff(), __builtin_inff()};
  }
  __shared__ unsigned s_vmax[2];
  __shared__ int s_widx[2];
  __shared__ float s_cd[2][3][16];
  if (tid == 0) {
    idx_out[b * 1024] = 0;
    s_vmax[0] = 0u;
    s_vmax[1] = 0u;
    s_widx[0] = 0x7fffffff;
    s_widx[1] = 0x7fffffff;
  }
  __syncthreads();
  float px = xb[0], py = xb[1], pz = xb[2];
  for (int it = 1; it < 1024; ++it) {
    int sl = it & 1;
    // ---- packed sweep: native f32x2 ops -> v_pk_add/v_pk_mul, no FMA
    f32x2 px2 = {px, px}, py2 = {py, py}, pz2 = {pz, pz};
    float tv = -1.0f;
#pragma unroll
    for (int q = 0; q < 8; ++q) {
      float4 t = xylds[(q << 10) + tid];  // {x0,x1,y0,y1}
      f32x2 X = {t.x, t.y};
      f32x2 Y = {t.z, t.w};
      f32x2 dx = X - px2;
      f32x2 dy = Y - py2;
      f32x2 dz = Z[q] - pz2;
      f32x2 d = dx * dx + dy * dy + dz * dz;  // ((dx2+dy2)+dz2), RN each op
      M[q].x = fminf(M[q].x, d.x);
      M[q].y = fminf(M[q].y, d.y);
      tv = fmaxf(fmaxf(tv, M[q].x), M[q].y);  // fuses to v_max3
    }
    // ---- wave max via DPP (lane 63), one LDS atomicMax per wave
    float bv = wave64_max_dpp(tv);
    if (lane == 63) atomicMax(&s_vmax[sl], (unsigned)__float_as_int(bv));
    __syncthreads();  // bar1: block max ready
    float v = __int_as_float((int)s_vmax[sl]);
    if (tid == 0) {  // reset other slot (readers passed bar1, writers wait bar2)
      s_vmax[sl ^ 1] = 0u;
      s_widx[sl ^ 1] = 0x7fffffff;
    }
    // ---- winner: lowest matching lane per wave -> atomicMin + coords to LDS
    unsigned long long mk = __ballot(tv == v);
    if (mk != 0ull && lane == (int)__builtin_ctzll(mk)) {
      int k = -1;
      float wx = 0.0f, wy = 0.0f, wz = 0.0f;
#pragma unroll
      for (int q = 0; q < 8; ++q) {  // ascending k, first match = lowest gid
        float4 t = xylds[(q << 10) + tid];
        if (k < 0 && M[q].x == v) { k = 2 * q;     wx = t.x; wy = t.z; wz = Z[q].x; }
        if (k < 0 && M[q].y == v) { k = 2 * q + 1; wx = t.y; wy = t.w; wz = Z[q].y; }
      }
      atomicMin(&s_widx[sl], ((base + k) << 4) | wid);
      s_cd[sl][0][wid] = wx;
      s_cd[sl][1][wid] = wy;
      s_cd[sl][2][wid] = wz;
    }
    __syncthreads();  // bar2: winner key + coords visible
    int kmin = s_widx[sl];
    int w = kmin & 15;
    int j = kmin >> 4;
    px = s_cd[sl][0][w];
    py = s_cd[sl][1][w];
    pz = s_cd[sl][2][w];
    if (tid == 0) idx_out[b * 1024 + it] = j;
  }
}

// ---------------- gather new_xyz into d_out[0 .. 24576) ----------------------
__global__ __launch_bounds__(256) void gather_newxyz(const float* __restrict__ xyz,
                                                     const int* __restrict__ idx,
                                                     float* __restrict__ out) {
  int t = blockIdx.x * 256 + threadIdx.x;  // 0..8191 = (b,p)
  int b = t >> 10;
  int i = idx[t];
  const float* src = xyz + ((size_t)b * 16384 + i) * 3;
  float* dst = out + (size_t)t * 3;
  dst[0] = src[0];
  dst[1] = src[1];
  dst[2] = src[2];
}

// ---------------- transpose features (B,64,N) -> (B,N,64) --------------------
__global__ __launch_bounds__(256) void transpose_feats(const float* __restrict__ f,
                                                       float* __restrict__ fT) {
  __shared__ float tile[64][65];
  int b = blockIdx.x >> 8;
  int n0 = (blockIdx.x & 255) << 6;
  int t = threadIdx.x;
  int nn = t & 63, c0 = t >> 6;
#pragma unroll
  for (int r = 0; r < 64; r += 4) {
    int c = c0 + r;
    tile[c][nn] = f[((size_t)b * 64 + c) * 16384 + n0 + nn];
  }
  __syncthreads();
  int cc = t & 63, n1 = t >> 6;
#pragma unroll
  for (int r = 0; r < 64; r += 4) {
    int n = n1 + r;
    fT[((size_t)b * 16384 + n0 + n) * 64 + cc] = tile[cc][n];
  }
}

// ---------------- ball query: one wave per centroid --------------------------
__global__ __launch_bounds__(256) void ballquery_kernel(const float* __restrict__ xyz,
                                                        const float* __restrict__ newxyz,
                                                        int* __restrict__ gidx) {
  int wid = threadIdx.x >> 6, lane = threadIdx.x & 63;
  int cid = blockIdx.x * 4 + wid;  // 0..8191
  int b = cid >> 10;
  const float* xb = xyz + (size_t)b * 16384 * 3;
  float cx = newxyz[cid * 3 + 0];
  float cy = newxyz[cid * 3 + 1];
  float cz = newxyz[cid * 3 + 2];
  int* out = gidx + (size_t)cid * 32;
  int found = 0;
  int first = -1;
  for (int c0 = 0; c0 < 16384; c0 += 64) {
    int g = c0 + lane;
    float xx = xb[g * 3 + 0], yy = xb[g * 3 + 1], zz = xb[g * 3 + 2];
    float d2 = sqd(xx, yy, zz, cx, cy, cz);
    bool inr = (d2 <= R2);
    unsigned long long mask = __ballot(inr);
    if (first < 0 && mask) first = c0 + (int)__builtin_ctzll(mask);
    int pre = __popcll(mask & ((1ull << lane) - 1ull));
    int slot = found + pre;
    if (inr && slot < 32) out[slot] = g;
    found += __popcll(mask);
    if (found >= 32) break;
  }
  for (int s = found + lane; s < 32; s += 64) out[s] = first;
}

// ---------------- fused group + MLP(67->64->64->128) + maxpool ---------------
#define FMA16(BASEPTR)                                                     \
  do {                                                                     \
    const float4* hp_ = (const float4*)(BASEPTR);                          \
    float4 v0 = hp_[0], v1 = hp_[1], v2 = hp_[2], v3 = hp_[3];             \
    float a = acc[s];                                                      \
    a = fmaf(w[0], v0.x, a);  a = fmaf(w[1], v0.y, a);                     \
    a = fmaf(w[2], v0.z, a);  a = fmaf(w[3], v0.w, a);                     \
    a = fmaf(w[4], v1.x, a);  a = fmaf(w[5], v1.y, a);                     \
    a = fmaf(w[6], v1.z, a);  a = fmaf(w[7], v1.w, a);                     \
    a = fmaf(w[8], v2.x, a);  a = fmaf(w[9], v2.y, a);                     \
    a = fmaf(w[10], v2.z, a); a = fmaf(w[11], v2.w, a);                    \
    a = fmaf(w[12], v3.x, a); a = fmaf(w[13], v3.y, a);                    \
    a = fmaf(w[14], v3.z, a); a = fmaf(w[15], v3.w, a);                    \
    acc[s] = a;                                                            \
  } while (0)

__global__ __launch_bounds__(256) void mlp_kernel(
    const float* __restrict__ xyz, const float* __restrict__ feats,
    const float* __restrict__ featsT, const float* __restrict__ newxyz,
    const int* __restrict__ gidx,
    const float* __restrict__ W1, const float* __restrict__ b1,
    const float* __restrict__ W2, const float* __restrict__ b2,
    const float* __restrict__ W3, const float* __restrict__ b3,
    float* __restrict__ out, int useT) {
  __shared__ float buf[4][32 * 68];
  int wid = threadIdx.x >> 6, lane = threadIdx.x & 63;
  int cid = blockIdx.x * 4 + wid;
  int b = cid >> 10, p = cid & 1023;
  float* A = buf[wid];
  const int* gi = gidx + (size_t)cid * 32;
  float cx = newxyz[cid * 3 + 0];
  float cy = newxyz[cid * 3 + 1];
  float cz = newxyz[cid * 3 + 2];

  // ---- stage h0
  if (useT) {
    const float4* fT4 = (const float4*)(featsT + (size_t)b * 16384 * 64);
    for (int t = lane; t < 512; t += 64) {
      int s = t >> 4, q = t & 15;
      int g = gi[s];
      float4 v = fT4[(size_t)g * 16 + q];
      *(float4*)(A + s * 68 + q * 4) = v;
    }
  } else {
    const float* fb = feats + (size_t)b * 64 * 16384;
    for (int t = lane; t < 2048; t += 64) {
      int c = t >> 5, s = t & 31;
      int g = gi[s];
      A[s * 68 + c] = fb[(size_t)c * 16384 + g];
    }
  }
  for (int t = lane; t < 96; t += 64) {
    int s = t / 3, c = t - s * 3;
    int g = gi[s];
    float pv = xyz[((size_t)b * 16384 + g) * 3 + c];
    float cv = (c == 0) ? cx : ((c == 1) ? cy : cz);
    A[s * 68 + 64 + c] = __fsub_rn(pv, cv);
  }
  if (lane < 32) A[lane * 68 + 67] = 0.0f;
  __syncthreads();

  int o = lane;
  float acc[32];

  // ---- L1: 67 -> 64
#pragma unroll
  for (int s = 0; s < 32; ++s) acc[s] = b1[o];
  {
    const float* wr = W1 + o * 67;
    for (int cb = 0; cb < 4; ++cb) {
      float w[16];
#pragma unroll
      for (int q = 0; q < 16; ++q) w[q] = wr[3 + cb * 16 + q];
#pragma unroll
      for (int s = 0; s < 32; ++s) { FMA16(A + s * 68 + cb * 16); }
    }
    float w0 = wr[0], w1 = wr[1], w2 = wr[2];
#pragma unroll
    for (int s = 0; s < 32; ++s) {
      float a = acc[s];
      a = fmaf(w0, A[s * 68 + 64], a);
      a = fmaf(w1, A[s * 68 + 65], a);
      a = fmaf(w2, A[s * 68 + 66], a);
      acc[s] = a;
    }
  }
  __syncthreads();
#pragma unroll
  for (int s = 0; s < 32; ++s) A[s * 64 + o] = fmaxf(acc[s], 0.0f);
  __syncthreads();

  // ---- L2: 64 -> 64
#pragma unroll
  for (int s = 0; s < 32; ++s) acc[s] = b2[o];
  {
    const float* wr = W2 + o * 64;
    for (int cb = 0; cb < 4; ++cb) {
      float w[16];
#pragma unroll
      for (int q = 0; q < 16; ++q) w[q] = wr[cb * 16 + q];
#pragma unroll
      for (int s = 0; s < 32; ++s) { FMA16(A + s * 64 + cb * 16); }
    }
  }
  __syncthreads();
#pragma unroll
  for (int s = 0; s < 32; ++s) A[s * 64 + o] = fmaxf(acc[s], 0.0f);
  __syncthreads();

  // ---- L3: 64 -> 128, fused relu + maxpool over s
  float* outp = out + 24576;
  for (int po = 0; po < 2; ++po) {
    int o2 = lane + (po << 6);
#pragma unroll
    for (int s = 0; s < 32; ++s) acc[s] = b3[o2];
    const float* wr = W3 + o2 * 64;
    for (int cb = 0; cb < 4; ++cb) {
      float w[16];
#pragma unroll
      for (int q = 0; q < 16; ++q) w[q] = wr[cb * 16 + q];
#pragma unroll
      for (int s = 0; s < 32; ++s) { FMA16(A + s * 64 + cb * 16); }
    }
    float mx = 0.0f;  // relu floor
#pragma unroll
    for (int s = 0; s < 32; ++s) mx = fmaxf(mx, acc[s]);
    outp[((size_t)b * 128 + o2) * 1024 + p] = mx;
  }
}

extern "C" void kernel_launch(void* const* d_in, const int* in_sizes, int n_in,
                              void* d_out, int out_size, void* d_ws, size_t ws_size,
                              hipStream_t stream) {
  const float* xyz = (const float*)d_in[0];
  const float* feats = (const float*)d_in[1];
  const float* W1 = (const float*)d_in[2];
  const float* b1 = (const float*)d_in[3];
  const float* W2 = (const float*)d_in[4];
  const float* b2 = (const float*)d_in[5];
  const float* W3 = (const float*)d_in[6];
  const float* b3 = (const float*)d_in[7];
  float* out = (float*)d_out;

  // ws layout: idx 32K | gidx 1M | xs/ys/zs 1.5M | featsT 32M (optional)
  int* idx = (int*)d_ws;
  int* gidx = (int*)((char*)d_ws + 32768);
  float* xs = (float*)((char*)d_ws + 32768 + 1048576);
  float* ys = xs + 131072;
  float* zs = ys + 131072;
  float* featsT = (float*)((char*)d_ws + 32768 + 1048576 + 1572864);
  size_t needT = 32768 + 1048576 + 1572864 +
                 (size_t)8 * 16384 * 64 * sizeof(float);
  int useT = (ws_size >= needT) ? 1 : 0;

  soa_kernel<<<512, 256, 0, stream>>>(xyz, xs, ys, zs);
  fps_kernel<<<8, 1024, 131072, stream>>>(xyz, xs, ys, zs, idx);
  gather_newxyz<<<32, 256, 0, stream>>>(xyz, idx, out);
  if (useT) transpose_feats<<<2048, 256, 0, stream>>>(feats, featsT);
  ballquery_kernel<<<2048, 256, 0, stream>>>(xyz, out, gidx);
  mlp_kernel<<<2048, 256, 0, stream>>>(xyz, feats, featsT, out, gidx,
                                       W1, b1, W2, b2, W3, b3, out, useT);
}